// Round 2
// baseline (911.604 us; speedup 1.0000x reference)
//
#include <hip/hip_runtime.h>
#include <hip/hip_bf16.h>

#define B_  32
#define P_  2048
#define C_  19
#define D_  512
#define H_  4
#define DH_ 128
#define BM  64
#define BLK 512
#define NROW (B_*P_)

typedef float f32x4 __attribute__((ext_vector_type(4)));
typedef short bf16x8 __attribute__((ext_vector_type(8)));

__device__ __forceinline__ unsigned short f2bf(float f) {
  unsigned int u = __float_as_uint(f);
  u += 0x7FFFu + ((u >> 16) & 1u);   // RNE
  return (unsigned short)(u >> 16);
}
__device__ __forceinline__ float bf2f(unsigned short h) {
  return __uint_as_float(((unsigned int)h) << 16);
}

// ---- prep: K/V (f32) + bf16 weight copies -------------------------------
__global__ __launch_bounds__(256) void prep_kernel(
    const float* __restrict__ ce,
    const float* __restrict__ Wq, const float* __restrict__ Wk,
    const float* __restrict__ bk, const float* __restrict__ Wv,
    const float* __restrict__ bv, const float* __restrict__ Wo,
    unsigned short* __restrict__ Wq_bf, unsigned short* __restrict__ Wo_bf,
    float* __restrict__ Kg, float* __restrict__ Vg)
{
  int g = blockIdx.x * 256 + threadIdx.x;          // 128*256 = 32768 threads
  for (int i = g; i < D_*D_; i += 32768) {
    Wq_bf[i] = f2bf(Wq[i]);
    Wo_bf[i] = f2bf(Wo[i]);
  }
  if (g < 2*C_*D_) {                               // 19456 dot-512s
    int which = (g >= C_*D_) ? 1 : 0;
    int idx = which ? (g - C_*D_) : g;
    int c = idx >> 9;
    int n = idx & (D_-1);
    const float* w = (which ? Wv : Wk) + (size_t)n * D_;
    const float* e = ce + (size_t)c * D_;
    float s = 0.f;
    #pragma unroll 8
    for (int d = 0; d < D_; ++d) s = fmaf(e[d], w[d], s);
    s += (which ? bv : bk)[n];
    if (which) Vg[idx] = s; else Kg[idx] = s;
  }
}

// ---- fused main ----------------------------------------------------------
__global__ __launch_bounds__(BLK) void fused_kernel(
    const float* __restrict__ x,
    const unsigned short* __restrict__ Wq_bf,
    const unsigned short* __restrict__ Wo_bf,
    const float* __restrict__ Kg, const float* __restrict__ Vg,
    const float* __restrict__ bq, const float* __restrict__ bo,
    const float* __restrict__ gamma, const float* __restrict__ beta,
    float* __restrict__ out)
{
  __shared__ unsigned short Xbf[BM][520];   // x tile, bf16
  __shared__ unsigned short AQ[BM][136];    // Q then attended (per head), bf16
  __shared__ float KhL[C_][132];
  __shared__ float VhL[C_][132];
  __shared__ float SC[BM][20];              // scores -> weights
  __shared__ float rsum[BM], rsumsq[BM], rmean[BM], rrstd[BM];

  const int t    = threadIdx.x;
  const int wave = t >> 6;
  const int lane = t & 63;
  const int lhi  = lane >> 4;
  const int llo  = lane & 15;
  const int row0 = blockIdx.x * BM;

  // stage X -> bf16 LDS (coalesced float4)
  {
    const float4* xv = (const float4*)(x + (size_t)row0 * D_);
    #pragma unroll
    for (int it = 0; it < (BM*D_/4)/BLK; ++it) {
      int i = it * BLK + t;
      int r = i >> 7;
      int c4 = (i & 127) << 2;
      float4 v = xv[i];
      unsigned int lo = (unsigned int)f2bf(v.x) | ((unsigned int)f2bf(v.y) << 16);
      unsigned int hi = (unsigned int)f2bf(v.z) | ((unsigned int)f2bf(v.w) << 16);
      unsigned int* p = (unsigned int*)&Xbf[r][c4];
      p[0] = lo; p[1] = hi;
    }
  }
  if (t < BM) { rsum[t] = 0.f; rsumsq[t] = 0.f; }

  f32x4 oacc[4][4];
  #pragma unroll
  for (int i = 0; i < 4; ++i)
    #pragma unroll
    for (int j = 0; j < 4; ++j)
      oacc[i][j] = (f32x4){0.f,0.f,0.f,0.f};

  const int tr = wave >> 1;          // Q-GEMM tile row (rows tr*16..)
  const int ch = (wave & 1) * 64;    // Q-GEMM col half within head

  for (int h = 0; h < H_; ++h) {
    __syncthreads();  // AQ/Kh/Vh free; Xbf ready (h==0)

    // stage K/V head slice (f32)
    for (int i = t; i < C_*DH_; i += BLK) {
      int c = i >> 7, d = i & (DH_-1);
      KhL[c][d] = Kg[c*D_ + h*DH_ + d];
      VhL[c][d] = Vg[c*D_ + h*DH_ + d];
    }

    // ---- Q = X @ Wq_h^T  (MFMA) ----
    f32x4 qacc[4];
    #pragma unroll
    for (int i = 0; i < 4; ++i) qacc[i] = (f32x4){0.f,0.f,0.f,0.f};
    #pragma unroll 4
    for (int ks = 0; ks < 16; ++ks) {
      int k = ks*32 + lhi*8;
      bf16x8 a = *(const bf16x8*)&Xbf[tr*16 + llo][k];
      #pragma unroll
      for (int tc = 0; tc < 4; ++tc) {
        int n = h*DH_ + ch + tc*16 + llo;
        bf16x8 b = *(const bf16x8*)&Wq_bf[(size_t)n*D_ + k];
        qacc[tc] = __builtin_amdgcn_mfma_f32_16x16x32_bf16(a, b, qacc[tc], 0, 0, 0);
      }
    }
    // write Q (+bq) -> AQ bf16
    #pragma unroll
    for (int tc = 0; tc < 4; ++tc) {
      int coln = ch + tc*16 + llo;
      float bqv = bq[h*DH_ + coln];
      #pragma unroll
      for (int r = 0; r < 4; ++r) {
        int m = tr*16 + lhi*4 + r;
        AQ[m][coln] = f2bf(qacc[tc][r] + bqv);
      }
    }
    __syncthreads();

    // ---- scores (VALU): 8 threads/row, 2-3 channels each ----
    {
      int m  = t >> 3;
      int c0 = t & 7;
      int c2 = (c0 < 3) ? (c0 + 16) : 0;   // clamped; store guarded
      float s0 = 0.f, s1 = 0.f, s2 = 0.f;
      for (int d = 0; d < DH_; d += 8) {
        bf16x8 qv = *(const bf16x8*)&AQ[m][d];
        #pragma unroll
        for (int j = 0; j < 8; ++j) {
          float q = bf2f((unsigned short)qv[j]);
          s0 = fmaf(q, KhL[c0    ][d+j], s0);
          s1 = fmaf(q, KhL[c0 + 8][d+j], s1);
          s2 = fmaf(q, KhL[c2    ][d+j], s2);
        }
      }
      const float scale = 0.08838834764831843f;  // 1/sqrt(128)
      SC[m][c0    ] = s0 * scale;
      SC[m][c0 + 8] = s1 * scale;
      if (c0 < 3) SC[m][c0 + 16] = s2 * scale;
    }
    __syncthreads();

    // ---- softmax over 19 channels (1 thread/row) ----
    if (t < BM) {
      float mx = SC[t][0];
      #pragma unroll
      for (int c = 1; c < C_; ++c) mx = fmaxf(mx, SC[t][c]);
      float sum = 0.f;
      #pragma unroll
      for (int c = 0; c < C_; ++c) { float e = __expf(SC[t][c] - mx); SC[t][c] = e; sum += e; }
      float inv = 1.f / sum;
      #pragma unroll
      for (int c = 0; c < C_; ++c) SC[t][c] *= inv;
    }
    __syncthreads();

    // ---- attended = W @ V_h (VALU) -> AQ bf16 ----
    {
      int m  = t >> 3;
      int d0 = t & 7;
      float w[C_];
      #pragma unroll
      for (int c = 0; c < C_; ++c) w[c] = SC[m][c];
      #pragma unroll 4
      for (int i2 = 0; i2 < 16; ++i2) {
        int d = d0 + (i2 << 3);
        float a = 0.f;
        #pragma unroll
        for (int c = 0; c < C_; ++c) a = fmaf(w[c], VhL[c][d], a);
        AQ[m][d] = f2bf(a);
      }
    }
    __syncthreads();

    // ---- out += attended_h @ Wo_h^T (MFMA, per-wave 64 cols) ----
    #pragma unroll
    for (int ks = 0; ks < 4; ++ks) {
      int k = ks*32 + lhi*8;
      bf16x8 a[4];
      #pragma unroll
      for (int tr2 = 0; tr2 < 4; ++tr2)
        a[tr2] = *(const bf16x8*)&AQ[tr2*16 + llo][k];
      #pragma unroll
      for (int tc = 0; tc < 4; ++tc) {
        int n = wave*64 + tc*16 + llo;
        bf16x8 b = *(const bf16x8*)&Wo_bf[(size_t)n*D_ + h*DH_ + k];
        #pragma unroll
        for (int tr2 = 0; tr2 < 4; ++tr2)
          oacc[tr2][tc] = __builtin_amdgcn_mfma_f32_16x16x32_bf16(a[tr2], b, oacc[tr2][tc], 0, 0, 0);
      }
    }
  } // heads

  __syncthreads();

  // ---- epilogue: +bo, +x (f32 re-read), LN ----
  #pragma unroll
  for (int tc = 0; tc < 4; ++tc) {
    int col = wave*64 + tc*16 + llo;
    float bov = bo[col];
    #pragma unroll
    for (int tr2 = 0; tr2 < 4; ++tr2) {
      #pragma unroll
      for (int r = 0; r < 4; ++r) {
        int m = tr2*16 + lhi*4 + r;
        float xres = x[(size_t)(row0 + m)*D_ + col];
        oacc[tr2][tc][r] += bov + xres;
      }
    }
  }
  // per-row sum/sumsq: reduce over 16 lanes (cols), atomics across waves
  #pragma unroll
  for (int tr2 = 0; tr2 < 4; ++tr2) {
    #pragma unroll
    for (int r = 0; r < 4; ++r) {
      float s = 0.f, q = 0.f;
      #pragma unroll
      for (int tc = 0; tc < 4; ++tc) {
        float v = oacc[tr2][tc][r];
        s += v; q = fmaf(v, v, q);
      }
      #pragma unroll
      for (int off = 1; off < 16; off <<= 1) {
        s += __shfl_xor(s, off, 64);
        q += __shfl_xor(q, off, 64);
      }
      if (llo == 0) {
        int m = tr2*16 + lhi*4 + r;
        atomicAdd(&rsum[m], s);
        atomicAdd(&rsumsq[m], q);
      }
    }
  }
  __syncthreads();
  if (t < BM) {
    float mean = rsum[t] * (1.f/(float)D_);
    float var  = rsumsq[t] * (1.f/(float)D_) - mean*mean;
    rmean[t] = mean;
    rrstd[t] = rsqrtf(var + 1e-5f);
  }
  __syncthreads();
  #pragma unroll
  for (int tc = 0; tc < 4; ++tc) {
    int col = wave*64 + tc*16 + llo;
    float g = gamma[col], bt = beta[col];
    #pragma unroll
    for (int tr2 = 0; tr2 < 4; ++tr2) {
      #pragma unroll
      for (int r = 0; r < 4; ++r) {
        int m = tr2*16 + lhi*4 + r;
        float y = (oacc[tr2][tc][r] - rmean[m]) * rrstd[m] * g + bt;
        out[(size_t)(row0 + m)*D_ + col] = y;
      }
    }
  }
}

extern "C" void kernel_launch(void* const* d_in, const int* in_sizes, int n_in,
                              void* d_out, int out_size, void* d_ws, size_t ws_size,
                              hipStream_t stream) {
  const float* x     = (const float*)d_in[0];
  const float* ce    = (const float*)d_in[1];
  const float* Wq    = (const float*)d_in[2];
  const float* bq    = (const float*)d_in[3];
  const float* Wk    = (const float*)d_in[4];
  const float* bk    = (const float*)d_in[5];
  const float* Wv    = (const float*)d_in[6];
  const float* bv    = (const float*)d_in[7];
  const float* Wo    = (const float*)d_in[8];
  const float* bo    = (const float*)d_in[9];
  const float* gamma = (const float*)d_in[10];
  const float* beta  = (const float*)d_in[11];
  float* out = (float*)d_out;

  char* ws = (char*)d_ws;
  unsigned short* Wq_bf = (unsigned short*)ws;                  // 512 KiB
  unsigned short* Wo_bf = (unsigned short*)(ws + 524288);       // 512 KiB
  float* Kg = (float*)(ws + 1048576);                           // 38912 B
  float* Vg = (float*)(ws + 1048576 + 38912);                   // 38912 B

  prep_kernel<<<128, 256, 0, stream>>>(ce, Wq, Wk, bk, Wv, bv, Wo,
                                       Wq_bf, Wo_bf, Kg, Vg);
  fused_kernel<<<NROW/BM, BLK, 0, stream>>>(x, Wq_bf, Wo_bf, Kg, Vg,
                                            bq, bo, gamma, beta, out);
}

// Round 3
// 216.293 us; speedup vs baseline: 4.2147x; 4.2147x over previous
//
#include <hip/hip_runtime.h>
#include <hip/hip_bf16.h>

#define B_  32
#define P_  2048
#define C_  19
#define D_  512
#define H_  4
#define DH_ 128
#define NROW (B_*P_)
#define CH_  76          // C_*H_
#define CHP_ 96          // padded K for out-GEMM (3x32)

typedef float f32x4 __attribute__((ext_vector_type(4)));
typedef short bf16x8 __attribute__((ext_vector_type(8)));

__device__ __forceinline__ unsigned short f2bf(float f) {
  unsigned int u = __float_as_uint(f);
  u += 0x7FFFu + ((u >> 16) & 1u);   // RNE
  return (unsigned short)(u >> 16);
}

// ---- prep1: K/V = ce @ W^T + b  (f32) ------------------------------------
__global__ __launch_bounds__(256) void prep1(
    const float* __restrict__ ce,
    const float* __restrict__ Wk, const float* __restrict__ bk,
    const float* __restrict__ Wv, const float* __restrict__ bv,
    float* __restrict__ Kg, float* __restrict__ Vg)
{
  int g = blockIdx.x * 256 + threadIdx.x;
  if (g >= 2*C_*D_) return;
  int which = (g >= C_*D_) ? 1 : 0;
  int idx = which ? (g - C_*D_) : g;
  int c = idx >> 9;
  int n = idx & (D_-1);
  const float* w = (which ? Wv : Wk) + (size_t)n * D_;
  const float* e = ce + (size_t)c * D_;
  float s = 0.f;
  #pragma unroll 8
  for (int d = 0; d < D_; ++d) s = fmaf(e[d], w[d], s);
  s += (which ? bv : bk)[n];
  if (which) Vg[idx] = s; else Kg[idx] = s;
}

// ---- prep2: M~[(h*19+c)][512], U_t[512][96], s0[80] -----------------------
// M~[ch][m] = (1/sqrt(128)) * sum_dh Wq[h*128+dh][m] * K[c][h*128+dh]
// U_t[m][ch] = sum_dh Wo[m][h*128+dh] * V[c][h*128+dh]
// s0[ch]    = (1/sqrt(128)) * sum_dh bq[h*128+dh] * K[c][h*128+dh]
__global__ __launch_bounds__(512) void prep2(
    const float* __restrict__ Wq, const float* __restrict__ bq,
    const float* __restrict__ Wo,
    const float* __restrict__ Kg, const float* __restrict__ Vg,
    unsigned short* __restrict__ Mt, unsigned short* __restrict__ Ut,
    float* __restrict__ s0g)
{
  int ch = blockIdx.x;   // 0..95
  int m  = threadIdx.x;  // 0..511
  if (ch >= CH_) {
    if (ch < 80) { Mt[ch*D_ + m] = 0; if (m == 0) s0g[ch] = 0.f; }
    Ut[(size_t)m*CHP_ + ch] = 0;
    return;
  }
  int h = ch / C_, c = ch % C_;
  const float rs128 = 0.08838834764831843f;  // 1/sqrt(128)
  const float* Kr = Kg + c*D_ + h*DH_;
  const float* Vr = Vg + c*D_ + h*DH_;

  float macc = 0.f;
  #pragma unroll 4
  for (int dh = 0; dh < DH_; ++dh)
    macc = fmaf(Wq[(size_t)(h*DH_+dh)*D_ + m], Kr[dh], macc);
  Mt[ch*D_ + m] = f2bf(macc * rs128);

  float uacc = 0.f;
  const float* wor = Wo + (size_t)m*D_ + h*DH_;
  #pragma unroll 4
  for (int dh = 0; dh < DH_; ++dh)
    uacc = fmaf(wor[dh], Vr[dh], uacc);
  Ut[(size_t)m*CHP_ + ch] = f2bf(uacc);

  if (m == 0) {
    float sa = 0.f;
    const float* bqr = bq + h*DH_;
    for (int dh = 0; dh < DH_; ++dh) sa = fmaf(bqr[dh], Kr[dh], sa);
    s0g[ch] = sa * rs128;
  }
}

// ---- fused main: S = x@M~^T (+s0) -> softmax -> out = W@U + x, LN ---------
// BM=32 rows/block, 256 threads (4 waves: rg=wave>>1 row-group, cs=wave&1 col-half)
__global__ __launch_bounds__(256) void fused_main(
    const float* __restrict__ x,
    const unsigned short* __restrict__ Mt,   // [80][512] bf16
    const unsigned short* __restrict__ Ut,   // [512][96] bf16
    const float* __restrict__ s0g,           // [80]
    const float* __restrict__ bo,
    const float* __restrict__ gamma, const float* __restrict__ beta,
    float* __restrict__ out)
{
  __shared__ float Sf[32][84];
  __shared__ unsigned short Wa[32][104];
  __shared__ float rs_[32][2], rq_[32][2];

  const int t    = threadIdx.x;
  const int wave = t >> 6;
  const int lane = t & 63;
  const int lhi  = lane >> 4;
  const int llo  = lane & 15;
  const int rg   = wave >> 1;
  const int cs   = wave & 1;
  const int row0 = blockIdx.x * 32;

  // ---- phase 1: S-GEMM (K=512). A-frags from global x (f32 -> bf16). ----
  bf16x8 af[16];
  {
    const float* xr = x + (size_t)(row0 + rg*16 + llo)*D_ + lhi*8;
    #pragma unroll
    for (int ks = 0; ks < 16; ++ks) {
      float4 v0 = *(const float4*)(xr + ks*32);
      float4 v1 = *(const float4*)(xr + ks*32 + 4);
      bf16x8 a;
      a[0]=(short)f2bf(v0.x); a[1]=(short)f2bf(v0.y);
      a[2]=(short)f2bf(v0.z); a[3]=(short)f2bf(v0.w);
      a[4]=(short)f2bf(v1.x); a[5]=(short)f2bf(v1.y);
      a[6]=(short)f2bf(v1.z); a[7]=(short)f2bf(v1.w);
      af[ks] = a;
    }
  }
  {
    const int nct = cs ? 2 : 3;
    const int ct0 = cs ? 3 : 0;
    for (int i = 0; i < nct; ++i) {
      int ct = ct0 + i;
      f32x4 sacc = (f32x4){0.f,0.f,0.f,0.f};
      const unsigned short* mrow = Mt + (size_t)(ct*16 + llo)*D_ + lhi*8;
      #pragma unroll
      for (int ks = 0; ks < 16; ++ks) {
        bf16x8 b = *(const bf16x8*)(mrow + ks*32);
        sacc = __builtin_amdgcn_mfma_f32_16x16x32_bf16(af[ks], b, sacc, 0, 0, 0);
      }
      #pragma unroll
      for (int r = 0; r < 4; ++r)
        Sf[rg*16 + lhi*4 + r][ct*16 + llo] = sacc[r];
    }
  }
  __syncthreads();

  // ---- phase 2: softmax over c per (row, h); zero pad cols of Wa ----
  if (t < 128) {
    int row = t >> 2, h = t & 3;
    float v[19];
    float mx = -1e30f;
    #pragma unroll
    for (int c = 0; c < C_; ++c) {
      v[c] = Sf[row][h*C_ + c] + s0g[h*C_ + c];
      mx = fmaxf(mx, v[c]);
    }
    float sum = 0.f;
    #pragma unroll
    for (int c = 0; c < C_; ++c) { float e = __expf(v[c] - mx); v[c] = e; sum += e; }
    float inv = 1.f / sum;
    #pragma unroll
    for (int c = 0; c < C_; ++c) Wa[row][h*C_ + c] = f2bf(v[c] * inv);
  } else {
    int t2 = t - 128;
    int row = t2 >> 2, g4 = t2 & 3;
    #pragma unroll
    for (int j = 0; j < 5; ++j) Wa[row][CH_ + g4*5 + j] = 0;
  }
  __syncthreads();

  // ---- phase 3: out-GEMM (K=96). A from Wa LDS, B from Ut (L2-hot). ----
  f32x4 oacc[16];
  #pragma unroll
  for (int i = 0; i < 16; ++i) oacc[i] = (f32x4){0.f,0.f,0.f,0.f};
  #pragma unroll
  for (int ks = 0; ks < 3; ++ks) {
    bf16x8 a = *(const bf16x8*)&Wa[rg*16 + llo][ks*32 + lhi*8];
    #pragma unroll
    for (int tile = 0; tile < 16; ++tile) {
      int n = cs*256 + tile*16 + llo;
      bf16x8 b = *(const bf16x8*)(Ut + (size_t)n*CHP_ + ks*32 + lhi*8);
      oacc[tile] = __builtin_amdgcn_mfma_f32_16x16x32_bf16(a, b, oacc[tile], 0, 0, 0);
    }
  }

  // ---- phase 4: +bo, +x residual, LN, store ----
  float s[4] = {0,0,0,0}, q[4] = {0,0,0,0};
  #pragma unroll
  for (int tile = 0; tile < 16; ++tile) {
    int n = cs*256 + tile*16 + llo;
    float bov = bo[n];
    #pragma unroll
    for (int r = 0; r < 4; ++r) {
      int m = rg*16 + lhi*4 + r;
      float val = oacc[tile][r] + bov + x[(size_t)(row0 + m)*D_ + n];
      oacc[tile][r] = val;
      s[r] += val;
      q[r] = fmaf(val, val, q[r]);
    }
  }
  #pragma unroll
  for (int r = 0; r < 4; ++r) {
    #pragma unroll
    for (int off = 1; off < 16; off <<= 1) {
      s[r] += __shfl_xor(s[r], off, 64);
      q[r] += __shfl_xor(q[r], off, 64);
    }
  }
  if (llo == 0) {
    #pragma unroll
    for (int r = 0; r < 4; ++r) {
      rs_[rg*16 + lhi*4 + r][cs] = s[r];
      rq_[rg*16 + lhi*4 + r][cs] = q[r];
    }
  }
  __syncthreads();
  float mean[4], rstd[4];
  #pragma unroll
  for (int r = 0; r < 4; ++r) {
    int m = rg*16 + lhi*4 + r;
    float sum = rs_[m][0] + rs_[m][1];
    float sq  = rq_[m][0] + rq_[m][1];
    float mu  = sum * (1.f/(float)D_);
    float var = sq * (1.f/(float)D_) - mu*mu;
    mean[r] = mu;
    rstd[r] = rsqrtf(var + 1e-5f);
  }
  #pragma unroll
  for (int tile = 0; tile < 16; ++tile) {
    int n = cs*256 + tile*16 + llo;
    float g = gamma[n], bt = beta[n];
    #pragma unroll
    for (int r = 0; r < 4; ++r) {
      int m = rg*16 + lhi*4 + r;
      out[(size_t)(row0 + m)*D_ + n] = (oacc[tile][r] - mean[r]) * rstd[r] * g + bt;
    }
  }
}

extern "C" void kernel_launch(void* const* d_in, const int* in_sizes, int n_in,
                              void* d_out, int out_size, void* d_ws, size_t ws_size,
                              hipStream_t stream) {
  const float* x     = (const float*)d_in[0];
  const float* ce    = (const float*)d_in[1];
  const float* Wq    = (const float*)d_in[2];
  const float* bq    = (const float*)d_in[3];
  const float* Wk    = (const float*)d_in[4];
  const float* bk    = (const float*)d_in[5];
  const float* Wv    = (const float*)d_in[6];
  const float* bv    = (const float*)d_in[7];
  const float* Wo    = (const float*)d_in[8];
  const float* bo    = (const float*)d_in[9];
  const float* gamma = (const float*)d_in[10];
  const float* beta  = (const float*)d_in[11];
  float* out = (float*)d_out;

  char* ws = (char*)d_ws;
  float* Kg           = (float*)(ws);                   // 19*512*4 = 38912
  float* Vg           = (float*)(ws + 40960);           // 38912
  unsigned short* Mt  = (unsigned short*)(ws + 81920);  // 80*512*2 = 81920
  unsigned short* Ut  = (unsigned short*)(ws + 163840); // 512*96*2 = 98304
  float* s0g          = (float*)(ws + 262144);          // 320

  prep1<<<(2*C_*D_ + 255)/256, 256, 0, stream>>>(ce, Wk, bk, Wv, bv, Kg, Vg);
  prep2<<<CHP_, 512, 0, stream>>>(Wq, bq, Wo, Kg, Vg, Mt, Ut, s0g);
  fused_main<<<NROW/32, 256, 0, stream>>>(x, Mt, Ut, s0g, bo, gamma, beta, out);
}